// Round 7
// baseline (575.384 us; speedup 1.0000x reference)
//
#include <hip/hip_runtime.h>
#include <hip/hip_bf16.h>
#include <math.h>

#define D 768
#define BQ 4
#define NQ 512
#define M_TOTAL (BQ*NQ)   // 2048
#define KSEL 64

typedef short bf16x8 __attribute__((ext_vector_type(8)));
typedef float f32x4  __attribute__((ext_vector_type(4)));
typedef float f32x16 __attribute__((ext_vector_type(16)));

// ---------- fp32 -> bf16 hi/lo split ----------
__device__ __forceinline__ void split1(float x, unsigned int& h, unsigned int& l)
{
    unsigned int u  = __float_as_uint(x);
    unsigned int hb = (u + 0x7fffu + ((u >> 16) & 1u)) & 0xffff0000u;  // RNE bf16
    h = hb >> 16;
    l = __float_as_uint(x - __uint_as_float(hb)) >> 16;                 // truncated residual
}

// =====================================================================
// FAST PATH
// =====================================================================

// ---------- fused: L2 inv-norm + hi/lo bf16 split, one wave per row ----------
__global__ void split_invnorm_kernel(const float* __restrict__ x, unsigned short* __restrict__ sp,
                                     float* __restrict__ inv, int rows_src, int rows_dst)
{
    int r    = (blockIdx.x * blockDim.x + threadIdx.x) >> 6;
    int lane = threadIdx.x & 63;
    if (r >= rows_dst) return;
    int src = r < rows_src ? r : rows_src - 1;      // clamp pad rows
    const float* row = x + (size_t)src * D;
    unsigned short* dh = sp + (size_t)r * (2*D);
    unsigned short* dl = dh + D;
    float ss = 0.f;
    #pragma unroll
    for (int s = 0; s < 3; ++s) {
        float4 v = *reinterpret_cast<const float4*>(row + s*256 + lane*4);
        ss += v.x*v.x + v.y*v.y + v.z*v.z + v.w*v.w;
        unsigned int h0,h1,h2,h3,l0,l1,l2,l3;
        split1(v.x,h0,l0); split1(v.y,h1,l1); split1(v.z,h2,l2); split1(v.w,h3,l3);
        ushort4 hv = make_ushort4((unsigned short)h0,(unsigned short)h1,(unsigned short)h2,(unsigned short)h3);
        ushort4 lv = make_ushort4((unsigned short)l0,(unsigned short)l1,(unsigned short)l2,(unsigned short)l3);
        *reinterpret_cast<ushort4*>(dh + s*256 + lane*4) = hv;
        *reinterpret_cast<ushort4*>(dl + s*256 + lane*4) = lv;
    }
    #pragma unroll
    for (int off = 32; off > 0; off >>= 1)
        ss += __shfl_xor(ss, off, 64);
    if (lane == 0 && r < rows_src)
        inv[r] = 1.0f / fmaxf(sqrtf(ss), 1e-12f);
}

// ---------- 256x256 4-phase split-bf16 MFMA GEMM (32x32x16), fused max+sum ----------
// 8 waves (2M x 4N), per-wave 128x64 = 4 m-frags x 2 n-frags of 32x32, BK=32 (2 ksteps).
// LDS slot: A 256 rows x 128B (hi|lo chunks, XOR-swizzled) = 32KB ; B same = 32KB.
// Double-buffered: 2 x 64KB = 128KB dynamic LDS (1 block/CU).
// Round-4 schedule (best, 413us): reads at phase top, lgkmcnt(0), stage 3/3/1/1,
// vmcnt(6) end-P1 / vmcnt(2) end-P3 — only the MFMA shape is changed this round.
#define GBM 256
#define GBN 256
#define GBK 32
#define GNT (D/GBK)     // 24
#define SLOT_B_OFF 32768
#define SLOT_SZ 65536

__device__ __forceinline__ void gload16(const unsigned short* g, char* l)
{
    __builtin_amdgcn_global_load_lds((const __attribute__((address_space(1))) void*)g,
                                     (__attribute__((address_space(3))) void*)l, 16, 0, 0);
}

__global__ __launch_bounds__(512, 2)
void fast_gemm(const unsigned short* __restrict__ Qsp, const unsigned short* __restrict__ Ksp,
               const float* __restrict__ invq, float* __restrict__ pmax, float* __restrict__ psum,
               int Vp, int gx)
{
    extern __shared__ char smem[];

    const int t    = threadIdx.x;
    const int lane = t & 63;
    const int w    = t >> 6;         // 0..7
    const int wr   = w >> 2;         // 0..1 (m)
    const int wc   = w & 3;          // 0..3 (v)

    // XCD-aware swizzle, m-dim fastest (8 consecutive u share one B panel)
    int lid = blockIdx.x;
    int u   = (lid & 7) * gx + (lid >> 3);
    const int by = u & 7;
    const int bx = u >> 3;
    const int m0 = by * GBM;
    const int v0 = bx * GBN;

    // ---- staging: per-lane pre-swizzled global source (unchanged) ----
    const int lrow = lane >> 3;                    // dest row within 8-row group
    const int cc   = (lane & 7) ^ lrow;            // logical chunk at this lane's slot
    const size_t goff = (size_t)lrow * (2*D) + (size_t)(cc >> 2) * D + (size_t)(cc & 3) * 8;

    const int rAbase = ((w & 3) << 3) + ((w >> 2) << 7);   // + j*32
    const int rBbase = w * 32;

    const unsigned short* gAsrc = Qsp + (size_t)(m0 + rAbase) * (2*D) + goff;
    const unsigned short* gBsrc = Ksp + (size_t)(v0 + rBbase) * (2*D) + goff;

    #define SAk(k_, sl_, j_) gload16(gAsrc + (k_) + (size_t)(j_)*32*(2*D), (sl_) + (rAbase + (j_)*32)*128)
    #define SBk(k_, sl_, j_) gload16(gBsrc + (k_) + (size_t)(j_)*8 *(2*D), (sl_) + SLOT_B_OFF + (rBbase + (j_)*8)*128)

    // ---- fragment read offsets (32x32x16: row=lane&31, kgrp=lane>>5) ----
    const int l31 = lane & 31;
    const int kg2 = lane >> 5;                 // 0..1
    const int x7  = lane & 7;
    // kstep s: hi chunk = kg2+2s, lo chunk = 4+kg2+2s ; phys = chunk ^ (row&7) = chunk ^ x7
    const int sH0 = ((kg2    ) ^ x7) * 16;
    const int sH1 = ((kg2 + 2) ^ x7) * 16;
    const int sL0 = ((kg2 + 4) ^ x7) * 16;
    const int sL1 = ((kg2 + 6) ^ x7) * 16;
    const int offA = (wr*128 + l31) * 128;                 // + mf*4096 + chunk
    const int offB = SLOT_B_OFF + (wc*64 + l31) * 128;     // + nf*4096 + chunk

    f32x16 acc[4][2];
    #pragma unroll
    for (int i = 0; i < 4; ++i)
        #pragma unroll
        for (int j = 0; j < 2; ++j)
            acc[i][j] = (f32x16)(0.f);

    // B fragments: [nf] x {kstep0, kstep1} x {hi, lo}
    bf16x8 B0h[2], B1h[2], B0l[2], B1l[2];

    char* sl0 = smem;
    char* sl1 = smem + SLOT_SZ;

    // ---- prologue: stage tile 0 in steady-state queue order ----
    SBk(0, sl0, 0); SBk(0, sl0, 1); SAk(0, sl0, 0);
    SBk(0, sl0, 2); SBk(0, sl0, 3); SAk(0, sl0, 1);
    SAk(0, sl0, 2); SAk(0, sl0, 3);
    asm volatile("s_waitcnt vmcnt(2)" ::: "memory");   // B x4 + A0 + A1 resident
    __builtin_amdgcn_s_barrier();

    #define PHASE(p_, STG, VMW) do {                                                         \
        const char* pA_ = scur + offA + (p_)*4096;                                           \
        bf16x8 Ah0 = *(const bf16x8*)(pA_ + sH0);                                            \
        bf16x8 Ah1 = *(const bf16x8*)(pA_ + sH1);                                            \
        bf16x8 Al0 = *(const bf16x8*)(pA_ + sL0);                                            \
        bf16x8 Al1 = *(const bf16x8*)(pA_ + sL1);                                            \
        STG;                                                                                 \
        __builtin_amdgcn_s_barrier();                                                        \
        asm volatile("s_waitcnt lgkmcnt(0)" ::: "memory");                                   \
        __builtin_amdgcn_sched_barrier(0);                                                   \
        __builtin_amdgcn_s_setprio(1);                                                       \
        _Pragma("unroll")                                                                    \
        for (int nf = 0; nf < 2; ++nf) {                                                     \
            bf16x8 bh0 = nf ? B1h[0] : B0h[0];                                               \
            bf16x8 bh1 = nf ? B1h[1] : B0h[1];                                               \
            bf16x8 bl0 = nf ? B1l[0] : B0l[0];                                               \
            bf16x8 bl1 = nf ? B1l[1] : B0l[1];                                               \
            acc[p_][nf] = __builtin_amdgcn_mfma_f32_32x32x16_bf16(Ah0, bh0, acc[p_][nf], 0,0,0); \
            acc[p_][nf] = __builtin_amdgcn_mfma_f32_32x32x16_bf16(Ah1, bh1, acc[p_][nf], 0,0,0); \
            acc[p_][nf] = __builtin_amdgcn_mfma_f32_32x32x16_bf16(Ah0, bl0, acc[p_][nf], 0,0,0); \
            acc[p_][nf] = __builtin_amdgcn_mfma_f32_32x32x16_bf16(Ah1, bl1, acc[p_][nf], 0,0,0); \
            acc[p_][nf] = __builtin_amdgcn_mfma_f32_32x32x16_bf16(Al0, bh0, acc[p_][nf], 0,0,0); \
            acc[p_][nf] = __builtin_amdgcn_mfma_f32_32x32x16_bf16(Al1, bh1, acc[p_][nf], 0,0,0); \
        }                                                                                    \
        __builtin_amdgcn_s_setprio(0);                                                       \
        VMW;                                                                                 \
        __builtin_amdgcn_s_barrier();                                                        \
    } while(0)

    for (int T = 0; T < GNT; ++T) {
        const bool st = (T + 1 < GNT);
        char* scur = (T & 1) ? sl1 : sl0;
        char* snxt = (T & 1) ? sl0 : sl1;
        const int k1 = (T + 1) * GBK;

        // phase 0: read all B frags (8 ds_reads) + A quadrant 0
        {
            const char* pB0 = scur + offB;
            const char* pB1 = scur + offB + 4096;
            B0h[0] = *(const bf16x8*)(pB0 + sH0);  B0h[1] = *(const bf16x8*)(pB0 + sH1);
            B0l[0] = *(const bf16x8*)(pB0 + sL0);  B0l[1] = *(const bf16x8*)(pB0 + sL1);
            B1h[0] = *(const bf16x8*)(pB1 + sH0);  B1h[1] = *(const bf16x8*)(pB1 + sH1);
            B1l[0] = *(const bf16x8*)(pB1 + sL0);  B1l[1] = *(const bf16x8*)(pB1 + sL1);
        }
        PHASE(0, { if (st) { SBk(k1,snxt,0); SBk(k1,snxt,1); SAk(k1,snxt,0); } }, );
        // phase 1 (end: free A2,A3 of current tile — counted, not 0, when staging)
        PHASE(1, { if (st) { SBk(k1,snxt,2); SBk(k1,snxt,3); SAk(k1,snxt,1); } },
                 { if (st) asm volatile("s_waitcnt vmcnt(6)" ::: "memory");
                   else    asm volatile("s_waitcnt vmcnt(0)" ::: "memory"); });
        // phase 2
        PHASE(2, { if (st) SAk(k1,snxt,2); }, );
        // phase 3 (end: free B x4 + A0 + A1 of NEXT tile)
        PHASE(3, { if (st) SAk(k1,snxt,3); },
                 { if (st) asm volatile("s_waitcnt vmcnt(2)" ::: "memory"); });
    }
    #undef PHASE
    #undef SAk
    #undef SBk

    // ---- epilogue: per-column max (node) and sum (graph), invq-scaled ----
    // C/D: col = lane&31, row(local 32) = (reg&3) + 8*(reg>>2) + 4*kg2
    __syncthreads();
    f32x4 iqv[4][4];
    #pragma unroll
    for (int mf = 0; mf < 4; ++mf)
        #pragma unroll
        for (int rq = 0; rq < 4; ++rq)
            iqv[mf][rq] = *(const f32x4*)(invq + m0 + wr*128 + mf*32 + 4*kg2 + 8*rq);

    float* redm = (float*)smem;        // [2][256]
    float* reds = redm + 512;          // [2][256]
    #pragma unroll
    for (int nf = 0; nf < 2; ++nf) {
        float pmv = -INFINITY, psv = 0.f;
        #pragma unroll
        for (int mf = 0; mf < 4; ++mf)
            #pragma unroll
            for (int rq = 0; rq < 4; ++rq)
                #pragma unroll
                for (int rr = 0; rr < 4; ++rr) {
                    float x = acc[mf][nf][rq*4+rr] * iqv[mf][rq][rr];
                    pmv = fmaxf(pmv, x);
                    psv += x;
                }
        pmv = fmaxf(pmv, __shfl_xor(pmv, 32, 64));
        psv += __shfl_xor(psv, 32, 64);
        if (lane < 32) {
            redm[wr*256 + wc*64 + nf*32 + l31] = pmv;
            reds[wr*256 + wc*64 + nf*32 + l31] = psv;
        }
    }
    __syncthreads();
    if (t < 256) {
        pmax[(size_t)by * Vp + v0 + t] = fmaxf(redm[t], redm[256+t]);
        psum[(size_t)by * Vp + v0 + t] = reds[t] + reds[256+t];
    }
}

// ---------- blend: node max over batch tiles + graph from psum ----------
__global__ void blend_kernel(const float* __restrict__ pmax, const float* __restrict__ psum,
                             const float* __restrict__ invk, const float* __restrict__ alpha_raw,
                             float* __restrict__ out_fused, float* __restrict__ out_alpha,
                             int V, int Vp)
{
    int v = blockIdx.x * 256 + threadIdx.x;
    float alpha = 1.0f / (1.0f + expf(-alpha_raw[0]));
    if (blockIdx.x == 0 && threadIdx.x == 0) out_alpha[0] = alpha;
    if (v >= V) return;
    float ik = invk[v];
    #pragma unroll
    for (int b = 0; b < BQ; ++b) {
        float nm = fmaxf(pmax[(size_t)(2*b)*Vp + v], pmax[(size_t)(2*b+1)*Vp + v]) * ik;
        float gs = (psum[(size_t)(2*b)*Vp + v] + psum[(size_t)(2*b+1)*Vp + v]) * ik * (1.0f/(float)NQ);
        out_fused[(size_t)b*V + v] = alpha*nm + (1.0f-alpha)*gs;
    }
}

// ---------- per-batch top-64 via 4-pass radix select + bitonic order ----------
__device__ __forceinline__ unsigned int mono_map(float f)
{
    unsigned int u = __float_as_uint(f);
    return u ^ ((u & 0x80000000u) ? 0xFFFFFFFFu : 0x80000000u);
}

__global__ __launch_bounds__(1024)
void topk_radix_kernel(const float* __restrict__ fused,
                       int* __restrict__ idxout, float* __restrict__ out_idx, int V)
{
    const int b = blockIdx.x, t = threadIdx.x;
    const float* row = fused + (size_t)b * V;

    __shared__ unsigned int hist[256];
    __shared__ unsigned int sh_pref;
    __shared__ int sh_kneed;
    __shared__ unsigned int sh_nA, sh_nE;
    __shared__ unsigned long long key[64];
    __shared__ int eqIdx[256];

    unsigned int pref = 0;
    int kneed = KSEL;
    #pragma unroll
    for (int p = 24; p >= 0; p -= 8) {
        if (t < 256) hist[t] = 0;
        __syncthreads();
        unsigned int mask = (p == 24) ? 0u : (0xFFFFFFFFu << (p + 8));
        for (int i = t; i < V; i += 1024) {
            unsigned int u = mono_map(row[i]);
            if ((u & mask) == pref)
                atomicAdd(&hist[(u >> p) & 255u], 1u);
        }
        __syncthreads();
        if (t == 0) {
            int cum = 0, sel = 0;
            for (int bb = 255; bb >= 0; --bb) {
                int c = (int)hist[bb];
                if (cum + c >= kneed) { sel = bb; break; }
                cum += c;
            }
            sh_pref  = pref | ((unsigned int)sel << p);
            sh_kneed = kneed - cum;
        }
        __syncthreads();
        pref  = sh_pref;
        kneed = sh_kneed;
        __syncthreads();
    }

    const unsigned int T = pref;            // exact 64th-largest mapped value
    if (t == 0) { sh_nA = 0; sh_nE = 0; }
    __syncthreads();
    for (int i = t; i < V; i += 1024) {
        unsigned int u = mono_map(row[i]);
        if (u > T) {
            unsigned int pos = atomicAdd(&sh_nA, 1u);
            if (pos < 64) key[pos] = ((unsigned long long)(~u) << 32) | (unsigned int)i;
        } else if (u == T) {
            unsigned int pos = atomicAdd(&sh_nE, 1u);
            if (pos < 256) eqIdx[pos] = i;
        }
    }
    __syncthreads();
    const int nA = (int)sh_nA;              // < 64 by radix invariant
    const int nE = (int)sh_nE;
    if (t < 256 && t >= min(nE, 256)) eqIdx[t] = 0x7fffffff;
    __syncthreads();
    if (nE > 1) {                            // sort tie indices ascending
        for (int k = 2; k <= 256; k <<= 1)
            for (int j = k >> 1; j > 0; j >>= 1) {
                if (t < 256) {
                    int ixj = t ^ j;
                    if (ixj > t) {
                        int a = eqIdx[t], c = eqIdx[ixj];
                        bool up = ((t & k) == 0);
                        if ((a > c) == up) { eqIdx[t] = c; eqIdx[ixj] = a; }
                    }
                }
                __syncthreads();
            }
    }
    if (t < kneed)
        key[nA + t] = ((unsigned long long)(~T) << 32) | (unsigned int)eqIdx[t];
    __syncthreads();
    // sort 64 keys ascending == (value desc, idx asc)
    for (int k = 2; k <= 64; k <<= 1)
        for (int j = k >> 1; j > 0; j >>= 1) {
            if (t < 64) {
                int ixj = t ^ j;
                if (ixj > t) {
                    unsigned long long a = key[t], c = key[ixj];
                    bool up = ((t & k) == 0);
                    if ((a > c) == up) { key[t] = c; key[ixj] = a; }
                }
            }
            __syncthreads();
        }
    if (t < KSEL) {
        int idx = (int)(unsigned int)(key[t] & 0xFFFFFFFFull);
        idxout[b*KSEL + t]  = idx;
        out_idx[b*KSEL + t] = (float)idx;
    }
}

// ---------- gather selected key rows ----------
__global__ void gather_kernel(const int* __restrict__ idx, const float* __restrict__ Kmat,
                              float* __restrict__ out_sel)
{
    int j = blockIdx.x & 63, b = blockIdx.x >> 6, t = threadIdx.x;
    int sel = idx[b*KSEL + j];
    float4 v = *reinterpret_cast<const float4*>(Kmat + (size_t)sel * D + t*4);
    *reinterpret_cast<float4*>(out_sel + ((size_t)(b*KSEL + j)) * D + t*4) = v;
}

// =====================================================================
// FALLBACK PATH (round-2, known-good) — used when ws_size is too small
// =====================================================================
#define BMT 128
#define BVT 128
#define NSTEP (D/32)

__global__ void row_invnorm_kernel(const float* __restrict__ x, float* __restrict__ inv, int rows)
{
    int wid  = (blockIdx.x * blockDim.x + threadIdx.x) >> 6;
    int lane = threadIdx.x & 63;
    if (wid >= rows) return;
    const float* r = x + (size_t)wid * D;
    float ss = 0.f;
    #pragma unroll
    for (int s = 0; s < 3; ++s) {
        float4 v = *reinterpret_cast<const float4*>(r + s*256 + lane*4);
        ss += v.x*v.x + v.y*v.y + v.z*v.z + v.w*v.w;
    }
    #pragma unroll
    for (int off = 32; off > 0; off >>= 1)
        ss += __shfl_xor(ss, off, 64);
    if (lane == 0) inv[wid] = 1.0f / fmaxf(sqrtf(ss), 1e-12f);
}

__global__ void compute_gq_kernel(const float* __restrict__ q, const float* __restrict__ invq,
                                  float* __restrict__ gq)
{
    int t = blockIdx.x * blockDim.x + threadIdx.x;
    if (t >= BQ*D) return;
    int b = t / D, d = t - b*D;
    float acc = 0.f;
    const float* qb = q + (size_t)b * NQ * D + d;
    const float* iq = invq + b*NQ;
    for (int n = 0; n < NQ; ++n)
        acc += iq[n] * qb[(size_t)n*D];
    gq[t] = acc * (1.0f/(float)NQ);
}

__device__ __forceinline__ void split8(float4 a, float4 b, uint4& hi, uint4& lo)
{
    unsigned int h0,h1,h2,h3,h4,h5,h6,h7, l0,l1,l2,l3,l4,l5,l6,l7;
    split1(a.x,h0,l0); split1(a.y,h1,l1); split1(a.z,h2,l2); split1(a.w,h3,l3);
    split1(b.x,h4,l4); split1(b.y,h5,l5); split1(b.z,h6,l6); split1(b.w,h7,l7);
    hi.x = h0 | (h1<<16); hi.y = h2 | (h3<<16); hi.z = h4 | (h5<<16); hi.w = h6 | (h7<<16);
    lo.x = l0 | (l1<<16); lo.y = l2 | (l3<<16); lo.z = l4 | (l5<<16); lo.w = l6 | (l7<<16);
}

__global__ __launch_bounds__(256)
void mfma_gemm_maxpool(const float* __restrict__ Q, const float* __restrict__ Kmat,
                       const float* __restrict__ invq, const float* __restrict__ invk,
                       float* __restrict__ partial, int V, int Vp)
{
    __shared__ __align__(16) unsigned short lds[16384];
    const int t    = threadIdx.x;
    const int lane = t & 63;
    const int w    = t >> 6;
    const int wr   = w >> 1;
    const int wc   = w & 1;
    const int v0   = blockIdx.x * BVT;
    const int m0   = blockIdx.y * BMT;

    const int srow = t >> 1;
    const int scol = (t & 1) * 16;
    const int c0   = (t & 1) * 2;
    const unsigned int ps0 = (c0     + (srow >> 1)) & 3;
    const unsigned int ps1 = (c0 + 1 + (srow >> 1)) & 3;
    const unsigned int wO0 = srow*32 + ps0*8;
    const unsigned int wO1 = srow*32 + ps1*8;

    const float* Ap = Q + (size_t)(m0 + srow) * D + scol;
    int vrow = v0 + srow; if (vrow > V-1) vrow = V-1;
    const float* Bp = Kmat + (size_t)vrow * D + scol;

    const int lr = lane & 15, kg = lane >> 4;
    const int arowb = wr*64 + lr;
    const int browb = wc*64 + lr;
    const unsigned int slotA = (kg + (arowb >> 1)) & 3;
    const unsigned int slotB = (kg + (browb >> 1)) & 3;
    const unsigned int offA = arowb*32 + slotA*8;
    const unsigned int offB = browb*32 + slotB*8;

    f32x4 acc[4][4];
    #pragma unroll
    for (int i = 0; i < 4; ++i)
        #pragma unroll
        for (int j = 0; j < 4; ++j)
            acc[i][j] = f32x4{0.f,0.f,0.f,0.f};

    float4 ra0,ra1,ra2,ra3, rb0,rb1,rb2,rb3;
    #define LOADSTEP(s_) do { \
        const float* ap_ = Ap + (s_)*32; const float* bp_ = Bp + (s_)*32; \
        ra0 = *(const float4*)(ap_);    ra1 = *(const float4*)(ap_+4); \
        ra2 = *(const float4*)(ap_+8);  ra3 = *(const float4*)(ap_+12); \
        rb0 = *(const float4*)(bp_);    rb1 = *(const float4*)(bp_+4); \
        rb2 = *(const float4*)(bp_+8);  rb3 = *(const float4*)(bp_+12); \
    } while(0)

    LOADSTEP(0);
    for (int s = 0; s < NSTEP; ++s) {
        uint4 ah0,al0, ah1,al1, bh0,bl0, bh1,bl1;
        split8(ra0,ra1, ah0,al0); split8(ra2,ra3, ah1,al1);
        split8(rb0,rb1, bh0,bl0); split8(rb2,rb3, bh1,bl1);
        __syncthreads();
        *(uint4*)&lds[        wO0] = ah0;  *(uint4*)&lds[ 4096 + wO0] = al0;
        *(uint4*)&lds[        wO1] = ah1;  *(uint4*)&lds[ 4096 + wO1] = al1;
        *(uint4*)&lds[ 8192 + wO0] = bh0;  *(uint4*)&lds[12288 + wO0] = bl0;
        *(uint4*)&lds[ 8192 + wO1] = bh1;  *(uint4*)&lds[12288 + wO1] = bl1;
        if (s + 1 < NSTEP) LOADSTEP(s + 1);
        __syncthreads();

        bf16x8 Ah[4], Al[4], Bh[4], Bl[4];
        #pragma unroll
        for (int fm = 0; fm < 4; ++fm) {
            unsigned int o = offA + fm*512;
            Ah[fm] = *(const bf16x8*)&lds[o];
            Al[fm] = *(const bf16x8*)&lds[4096 + o];
        }
        #pragma unroll
        for (int fv = 0; fv < 4; ++fv) {
            unsigned int o = offB + fv*512;
            Bh[fv] = *(const bf16x8*)&lds[8192 + o];
            Bl[fv] = *(const bf16x8*)&lds[12288 + o];
        }
        #pragma unroll
        for (int fm = 0; fm < 4; ++fm)
            #pragma unroll
            for (int fv = 0; fv < 4; ++fv) {
                acc[fm][fv] = __builtin_amdgcn_mfma_f32_16x16x32_bf16(Ah[fm], Bh[fv], acc[fm][fv], 0,0,0);
                acc[fm][fv] = __builtin_amdgcn_mfma_f32_16x16x32_bf16(Ah[fm], Bl[fv], acc[fm][fv], 0,0,0);
                acc[fm][fv] = __builtin_amdgcn_mfma_f32_16x16x32_bf16(Al[fm], Bh[fv], acc[fm][fv], 0,0,0);
            }
    }
    #undef LOADSTEP

    __syncthreads();
    float* red = (float*)lds;
    float iq[4][4];
    #pragma unroll
    for (int fm = 0; fm < 4; ++fm)
        #pragma unroll
        for (int r = 0; r < 4; ++r)
            iq[fm][r] = invq[m0 + wr*64 + fm*16 + kg*4 + r];
    #pragma unroll
    for (int fv = 0; fv < 4; ++fv) {
        float tm = -INFINITY;
        #pragma unroll
        for (int fm = 0; fm < 4; ++fm)
            #pragma unroll
            for (int r = 0; r < 4; ++r)
                tm = fmaxf(tm, acc[fm][fv][r] * iq[fm][r]);
        tm = fmaxf(tm, __shfl_xor(tm, 16, 64));
        tm = fmaxf(tm, __shfl_xor(tm, 32, 64));
        if (lane < 16) red[wr*128 + wc*64 + fv*16 + lane] = tm;
    }
    __syncthreads();
    if (t < 128) {
        int v = v0 + t;
        if (v < V)
            partial[(size_t)blockIdx.y * Vp + v] = fmaxf(red[t], red[128 + t]) * invk[v];
    }
}

__global__ void fused_sim_kernel(const float* __restrict__ Kmat, const float* __restrict__ invk,
                                 const float* __restrict__ gq, const float* __restrict__ partial,
                                 const float* __restrict__ alpha_raw,
                                 float* __restrict__ out_fused, float* __restrict__ out_alpha,
                                 int V, int Vp)
{
    int wib  = threadIdx.x >> 6;
    int lane = threadIdx.x & 63;
    float alpha = 1.0f / (1.0f + expf(-alpha_raw[0]));
    if (blockIdx.x == 0 && threadIdx.x == 0) out_alpha[0] = alpha;
    int v = blockIdx.x * 4 + wib;
    if (v >= V) return;
    const float* kr = Kmat + (size_t)v * D;
    float accb[BQ] = {0.f,0.f,0.f,0.f};
    #pragma unroll
    for (int s = 0; s < 3; ++s) {
        float4 kv = *reinterpret_cast<const float4*>(kr + s*256 + lane*4);
        #pragma unroll
        for (int b = 0; b < BQ; ++b) {
            float4 gv = *reinterpret_cast<const float4*>(gq + b*D + s*256 + lane*4);
            accb[b] += gv.x*kv.x + gv.y*kv.y + gv.z*kv.z + gv.w*kv.w;
        }
    }
    #pragma unroll
    for (int b = 0; b < BQ; ++b)
        #pragma unroll
        for (int off = 32; off > 0; off >>= 1)
            accb[b] += __shfl_xor(accb[b], off, 64);
    if (lane < BQ) {
        int b = lane;
        float node = partial[(size_t)(b*4+0)*Vp + v];
        #pragma unroll
        for (int i = 1; i < 4; ++i)
            node = fmaxf(node, partial[(size_t)(b*4+i)*Vp + v]);
        float graph = accb[b] * invk[v];
        out_fused[(size_t)b*V + v] = alpha*node + (1.0f-alpha)*graph;
    }
}

__global__ __launch_bounds__(1024)
void topk_gather_kernel(const float* __restrict__ fused, const float* __restrict__ Kmat,
                        float* __restrict__ scratch, float* __restrict__ out_sel,
                        float* __restrict__ out_idx, int V, int Vp)
{
    const int b = blockIdx.x, t = threadIdx.x;
    const int lane = t & 63, wid = t >> 6;
    const float* row = fused + (size_t)b * V;
    float* s = scratch + (size_t)b * Vp;
    for (int i = t; i < V; i += 1024) s[i] = row[i];
    __syncthreads();

    const int CH = (V + 1023) / 1024;
    const int lo = t * CH;
    const int hi = min(V, lo + CH);
    float lmax = -INFINITY; int lidx = 0x7fffffff;
    for (int i = lo; i < hi; ++i) { float x = s[i]; if (x > lmax) { lmax = x; lidx = i; } }

    __shared__ float swv[16];
    __shared__ int   swi[16];
    __shared__ int   sbest;

    for (int j = 0; j < KSEL; ++j) {
        float v = lmax; int id = lidx;
        #pragma unroll
        for (int off = 32; off > 0; off >>= 1) {
            float ov = __shfl_xor(v, off, 64);
            int   oi = __shfl_xor(id, off, 64);
            if (ov > v || (ov == v && oi < id)) { v = ov; id = oi; }
        }
        if (lane == 0) { swv[wid] = v; swi[wid] = id; }
        __syncthreads();
        if (t == 0) {
            float bv = swv[0]; int bi = swi[0];
            for (int x = 1; x < 16; ++x)
                if (swv[x] > bv || (swv[x] == bv && swi[x] < bi)) { bv = swv[x]; bi = swi[x]; }
            sbest = bi;
            out_idx[b*KSEL + j] = (float)bi;
        }
        __syncthreads();
        const int sel = sbest;
        if (sel >= lo && sel < hi) {
            s[sel] = -INFINITY;
            lmax = -INFINITY; lidx = 0x7fffffff;
            for (int i = lo; i < hi; ++i) { float x = s[i]; if (x > lmax) { lmax = x; lidx = i; } }
        }
        if (t < 192) {
            float4 kv = *reinterpret_cast<const float4*>(&Kmat[(size_t)sel * D + t*4]);
            *reinterpret_cast<float4*>(&out_sel[((size_t)b*KSEL + j)*D + t*4]) = kv;
        }
        __syncthreads();
    }
}

// =====================================================================
extern "C" void kernel_launch(void* const* d_in, const int* in_sizes, int n_in,
                              void* d_out, int out_size, void* d_ws, size_t ws_size,
                              hipStream_t stream)
{
    const float* q         = (const float*)d_in[0];
    const float* kemb      = (const float*)d_in[1];
    const float* alpha_raw = (const float*)d_in[2];
    int V = in_sizes[1] / D;

    float* out_sel   = (float*)d_out;
    float* out_idx   = out_sel + BQ*KSEL*D;
    float* out_fused = out_idx + BQ*KSEL;
    float* out_alpha = out_fused + (size_t)BQ*V;

    // ---------- fast-path workspace layout ----------
    size_t Vp = (size_t)((V + 255) & ~255);
    float* ws      = (float*)d_ws;
    float* invk    = ws;                               // Vp
    float* invq    = invk + Vp;                        // M_TOTAL
    float* pmax    = invq + M_TOTAL;                   // 8*Vp
    float* psum    = pmax + 8*Vp;                      // 8*Vp
    float* scratch = psum + 8*Vp;                      // 4*Vp (unused in fast path)
    int*   idxbuf  = (int*)(scratch + 4*Vp);           // 256
    unsigned short* Qsp = (unsigned short*)(idxbuf + 256);      // M_TOTAL*1536
    unsigned short* Ksp = Qsp + (size_t)M_TOTAL * (2*D);        // Vp*1536
    size_t need = (size_t)((char*)(Ksp + Vp*(2*D)) - (char*)d_ws);

    if (ws_size >= need) {
        // ---------- FAST PATH ----------
        split_invnorm_kernel<<<M_TOTAL/4, 256, 0, stream>>>(q, Qsp, invq, M_TOTAL, M_TOTAL);
        split_invnorm_kernel<<<(int)(Vp/4), 256, 0, stream>>>(kemb, Ksp, invk, V, (int)Vp);

        hipFuncSetAttribute(reinterpret_cast<const void*>(fast_gemm),
                            hipFuncAttributeMaxDynamicSharedMemorySize, 2*SLOT_SZ);

        int gx = (int)(Vp / GBN);                      // Vp mult of 256
        fast_gemm<<<gx*8, 512, 2*SLOT_SZ, stream>>>(Qsp, Ksp, invq, pmax, psum, (int)Vp, gx);

        blend_kernel<<<(V + 255)/256, 256, 0, stream>>>(pmax, psum, invk, alpha_raw,
                                                        out_fused, out_alpha, V, (int)Vp);
        topk_radix_kernel<<<BQ, 1024, 0, stream>>>(out_fused, idxbuf, out_idx, V);
        gather_kernel<<<BQ*KSEL, 192, 0, stream>>>(idxbuf, kemb, out_sel);
    } else {
        // ---------- FALLBACK (round-2) ----------
        int Vp2 = (V + 127) & ~127;
        float* f_invk    = ws;
        float* f_invq    = f_invk + Vp2;
        float* f_gq      = f_invq + M_TOTAL;
        float* f_partial = f_gq + BQ*D;
        float* f_scratch = f_partial + (size_t)16*Vp2;

        row_invnorm_kernel<<<(V + 3)/4, 256, 0, stream>>>(kemb, f_invk, V);
        row_invnorm_kernel<<<(M_TOTAL + 3)/4, 256, 0, stream>>>(q, f_invq, M_TOTAL);
        compute_gq_kernel<<<(BQ*D + 255)/256, 256, 0, stream>>>(q, f_invq, f_gq);

        dim3 g(Vp2 / BVT, M_TOTAL / BMT);
        mfma_gemm_maxpool<<<g, 256, 0, stream>>>(q, kemb, f_invq, f_invk, f_partial, V, Vp2);

        fused_sim_kernel<<<(V + 3)/4, 256, 0, stream>>>(kemb, f_invk, f_gq, f_partial, alpha_raw,
                                                        out_fused, out_alpha, V, Vp2);
        topk_gather_kernel<<<BQ, 1024, 0, stream>>>(out_fused, kemb, f_scratch, out_sel, out_idx, V, Vp2);
    }
}

// Round 8
// 523.351 us; speedup vs baseline: 1.0994x; 1.0994x over previous
//
#include <hip/hip_runtime.h>
#include <hip/hip_bf16.h>
#include <math.h>

#define D 768
#define BQ 4
#define NQ 512
#define M_TOTAL (BQ*NQ)   // 2048
#define KSEL 64

typedef short bf16x8 __attribute__((ext_vector_type(8)));
typedef float f32x4  __attribute__((ext_vector_type(4)));

// ---------- fp32 -> bf16 hi/lo split ----------
__device__ __forceinline__ void split1(float x, unsigned int& h, unsigned int& l)
{
    unsigned int u  = __float_as_uint(x);
    unsigned int hb = (u + 0x7fffu + ((u >> 16) & 1u)) & 0xffff0000u;  // RNE bf16
    h = hb >> 16;
    l = __float_as_uint(x - __uint_as_float(hb)) >> 16;                 // truncated residual
}

// =====================================================================
// FAST PATH
// =====================================================================

// ---------- fused: L2 inv-norm + hi/lo bf16 split ----------
// 768 threads/block = 8 rows/block; thread owns 8 consecutive floats.
// 16B loads (2x float4) and 16B stores (uint4 per plane). Norm via LDS reduce.
__global__ __launch_bounds__(768)
void split_invnorm_kernel(const float* __restrict__ x, unsigned short* __restrict__ sp,
                          float* __restrict__ inv, int rows_src, int rows_dst)
{
    __shared__ float red[768];
    const int tid  = threadIdx.x;
    const int rloc = tid / 96;               // 0..7
    const int c    = (tid % 96) * 8;         // 0..760
    const int row  = blockIdx.x * 8 + rloc;
    if (row >= rows_dst) return;
    const int src  = row < rows_src ? row : rows_src - 1;   // clamp pad rows

    const float* rp = x + (size_t)src * D + c;
    float4 a = *reinterpret_cast<const float4*>(rp);
    float4 b = *reinterpret_cast<const float4*>(rp + 4);

    unsigned int h0,h1,h2,h3,h4,h5,h6,h7, l0,l1,l2,l3,l4,l5,l6,l7;
    split1(a.x,h0,l0); split1(a.y,h1,l1); split1(a.z,h2,l2); split1(a.w,h3,l3);
    split1(b.x,h4,l4); split1(b.y,h5,l5); split1(b.z,h6,l6); split1(b.w,h7,l7);
    uint4 hv, lv;
    hv.x = h0 | (h1<<16); hv.y = h2 | (h3<<16); hv.z = h4 | (h5<<16); hv.w = h6 | (h7<<16);
    lv.x = l0 | (l1<<16); lv.y = l2 | (l3<<16); lv.z = l4 | (l5<<16); lv.w = l6 | (l7<<16);

    unsigned short* dh = sp + (size_t)row * (2*D) + c;
    *reinterpret_cast<uint4*>(dh)     = hv;
    *reinterpret_cast<uint4*>(dh + D) = lv;

    float ss = a.x*a.x + a.y*a.y + a.z*a.z + a.w*a.w
             + b.x*b.x + b.y*b.y + b.z*b.z + b.w*b.w;
    red[tid] = ss;
    __syncthreads();
    if ((tid % 96) == 0 && row < rows_src) {
        float s = 0.f;
        #pragma unroll
        for (int j = 0; j < 96; ++j) s += red[rloc*96 + j];
        inv[row] = 1.0f / fmaxf(sqrtf(s), 1e-12f);
    }
}

// ---------- 256x256 4-phase split-bf16 MFMA GEMM, fused max+sum epilogues ----------
// (round-4 schedule, verbatim — best measured: 413us, MfmaUtil 53%, 0 conflicts)
// 8 waves (2M x 4N), per-wave 128x64 (8 m-frags x 4 n-frags), BK=32.
// LDS slot: A 256 rows x 128B (hi|lo chunks, XOR-swizzled) = 32KB ; B same = 32KB.
// Double-buffered: 2 x 64KB = 128KB dynamic LDS (1 block/CU).
// gload queue per K-tile = [B B A0 B B A1 A2 A3]; vmcnt(6) end-P1, vmcnt(2) end-P3.
#define GBM 256
#define GBN 256
#define GBK 32
#define GNT (D/GBK)     // 24
#define SLOT_B_OFF 32768
#define SLOT_SZ 65536

__device__ __forceinline__ void gload16(const unsigned short* g, char* l)
{
    __builtin_amdgcn_global_load_lds((const __attribute__((address_space(1))) void*)g,
                                     (__attribute__((address_space(3))) void*)l, 16, 0, 0);
}

__global__ __launch_bounds__(512, 2)
void fast_gemm(const unsigned short* __restrict__ Qsp, const unsigned short* __restrict__ Ksp,
               const float* __restrict__ invq, float* __restrict__ pmax, float* __restrict__ psum,
               int Vp, int gx)
{
    extern __shared__ char smem[];

    const int t    = threadIdx.x;
    const int lane = t & 63;
    const int w    = t >> 6;         // 0..7
    const int wr   = w >> 2;         // 0..1 (m)
    const int wc   = w & 3;          // 0..3 (v)

    // XCD-aware swizzle, m-dim fastest (8 consecutive u share one B panel)
    int lid = blockIdx.x;
    int u   = (lid & 7) * gx + (lid >> 3);
    const int by = u & 7;
    const int bx = u >> 3;
    const int m0 = by * GBM;
    const int v0 = bx * GBN;

    // ---- staging: per-lane pre-swizzled global source ----
    const int lrow = lane >> 3;                    // dest row within 8-row group
    const int cc   = (lane & 7) ^ lrow;            // logical chunk at this lane's slot
    const size_t goff = (size_t)lrow * (2*D) + (size_t)(cc >> 2) * D + (size_t)(cc & 3) * 8;

    const int rAbase = ((w & 3) << 3) + ((w >> 2) << 7);   // + j*32
    const int rBbase = w * 32;

    const unsigned short* gAsrc = Qsp + (size_t)(m0 + rAbase) * (2*D) + goff;
    const unsigned short* gBsrc = Ksp + (size_t)(v0 + rBbase) * (2*D) + goff;

    #define SAk(k_, sl_, j_) gload16(gAsrc + (k_) + (size_t)(j_)*32*(2*D), (sl_) + (rAbase + (j_)*32)*128)
    #define SBk(k_, sl_, j_) gload16(gBsrc + (k_) + (size_t)(j_)*8 *(2*D), (sl_) + SLOT_B_OFF + (rBbase + (j_)*8)*128)

    // ---- fragment read offsets (swizzle matches staging) ----
    const int l15 = lane & 15, kg = lane >> 4;
    const int sHi = ((kg    ) ^ (lane & 7)) * 16;
    const int sLo = ((kg + 4) ^ (lane & 7)) * 16;
    const int offA = (wr*128 + l15) * 128;               // + mf*2048 + sHi/sLo
    const int offB = SLOT_B_OFF + (wc*64 + l15) * 128;   // + nf*2048 + sHi/sLo

    f32x4 acc[8][4];
    #pragma unroll
    for (int i = 0; i < 8; ++i)
        #pragma unroll
        for (int j = 0; j < 4; ++j)
            acc[i][j] = f32x4{0.f,0.f,0.f,0.f};

    bf16x8 Bh[4], Bl[4];

    char* sl0 = smem;
    char* sl1 = smem + SLOT_SZ;

    // ---- prologue: stage tile 0 in steady-state queue order ----
    SBk(0, sl0, 0); SBk(0, sl0, 1); SAk(0, sl0, 0);
    SBk(0, sl0, 2); SBk(0, sl0, 3); SAk(0, sl0, 1);
    SAk(0, sl0, 2); SAk(0, sl0, 3);
    asm volatile("s_waitcnt vmcnt(2)" ::: "memory");   // B x4 + A0 + A1 resident
    __builtin_amdgcn_s_barrier();

    #define PHASE(p_, STG, VMW) do {                                                         \
        bf16x8 Ah0 = *(const bf16x8*)(scur + offA + (2*(p_)  )*2048 + sHi);                  \
        bf16x8 Al0 = *(const bf16x8*)(scur + offA + (2*(p_)  )*2048 + sLo);                  \
        bf16x8 Ah1 = *(const bf16x8*)(scur + offA + (2*(p_)+1)*2048 + sHi);                  \
        bf16x8 Al1 = *(const bf16x8*)(scur + offA + (2*(p_)+1)*2048 + sLo);                  \
        STG;                                                                                 \
        __builtin_amdgcn_s_barrier();                                                        \
        asm volatile("s_waitcnt lgkmcnt(0)" ::: "memory");                                   \
        __builtin_amdgcn_s_setprio(1);                                                       \
        _Pragma("unroll")                                                                    \
        for (int nf = 0; nf < 4; ++nf) {                                                     \
            acc[2*(p_)  ][nf] = __builtin_amdgcn_mfma_f32_16x16x32_bf16(Ah0, Bh[nf], acc[2*(p_)  ][nf], 0,0,0); \
            acc[2*(p_)+1][nf] = __builtin_amdgcn_mfma_f32_16x16x32_bf16(Ah1, Bh[nf], acc[2*(p_)+1][nf], 0,0,0); \
        }                                                                                    \
        _Pragma("unroll")                                                                    \
        for (int nf = 0; nf < 4; ++nf) {                                                     \
            acc[2*(p_)  ][nf] = __builtin_amdgcn_mfma_f32_16x16x32_bf16(Ah0, Bl[nf], acc[2*(p_)  ][nf], 0,0,0); \
            acc[2*(p_)+1][nf] = __builtin_amdgcn_mfma_f32_16x16x32_bf16(Ah1, Bl[nf], acc[2*(p_)+1][nf], 0,0,0); \
        }                                                                                    \
        _Pragma("unroll")                                                                    \
        for (int nf = 0; nf < 4; ++nf) {                                                     \
            acc[2*(p_)  ][nf] = __builtin_amdgcn_mfma_f32_16x16x32_bf16(Al0, Bh[nf], acc[2*(p_)  ][nf], 0,0,0); \
            acc[2*(p_)+1][nf] = __builtin_amdgcn_mfma_f32_16x16x32_bf16(Al1, Bh[nf], acc[2*(p_)+1][nf], 0,0,0); \
        }                                                                                    \
        __builtin_amdgcn_s_setprio(0);                                                       \
        VMW;                                                                                 \
        __builtin_amdgcn_s_barrier();                                                        \
    } while(0)

    for (int T = 0; T < GNT; ++T) {
        const bool st = (T + 1 < GNT);
        char* scur = (T & 1) ? sl1 : sl0;
        char* snxt = (T & 1) ? sl0 : sl1;
        const int k1 = (T + 1) * GBK;

        // phase 0: B frags (once per K-step) + A quadrant 0
        #pragma unroll
        for (int nf = 0; nf < 4; ++nf) {
            Bh[nf] = *(const bf16x8*)(scur + offB + nf*2048 + sHi);
            Bl[nf] = *(const bf16x8*)(scur + offB + nf*2048 + sLo);
        }
        PHASE(0, { if (st) { SBk(k1, snxt, 0); SBk(k1, snxt, 1); SAk(k1, snxt, 0); } }, );
        // phase 1 (end: free A2,A3 of current tile — counted, not 0, when staging)
        PHASE(1, { if (st) { SBk(k1, snxt, 2); SBk(k1, snxt, 3); SAk(k1, snxt, 1); } },
                 { if (st) asm volatile("s_waitcnt vmcnt(6)" ::: "memory");
                   else    asm volatile("s_waitcnt vmcnt(0)" ::: "memory"); });
        // phase 2
        PHASE(2, { if (st) SAk(k1, snxt, 2); }, );
        // phase 3 (end: free B x4 + A0 + A1 of NEXT tile)
        PHASE(3, { if (st) SAk(k1, snxt, 3); },
                 { if (st) asm volatile("s_waitcnt vmcnt(2)" ::: "memory"); });
    }
    #undef PHASE
    #undef SAk
    #undef SBk

    // ---- epilogue: per-column max (node) and sum (graph), invq-scaled ----
    __syncthreads();
    float iq[32];
    #pragma unroll
    for (int mf = 0; mf < 8; ++mf)
        #pragma unroll
        for (int r = 0; r < 4; ++r)
            iq[mf*4+r] = invq[m0 + wr*128 + mf*16 + kg*4 + r];

    float* redm = (float*)smem;        // [2][256]
    float* reds = redm + 512;          // [2][256]
    #pragma unroll
    for (int nf = 0; nf < 4; ++nf) {
        float pmv = -INFINITY, psv = 0.f;
        #pragma unroll
        for (int mf = 0; mf < 8; ++mf)
            #pragma unroll
            for (int r = 0; r < 4; ++r) {
                float x = acc[mf][nf][r] * iq[mf*4+r];
                pmv = fmaxf(pmv, x);
                psv += x;
            }
        pmv = fmaxf(pmv, __shfl_xor(pmv, 16, 64));
        pmv = fmaxf(pmv, __shfl_xor(pmv, 32, 64));
        psv += __shfl_xor(psv, 16, 64);
        psv += __shfl_xor(psv, 32, 64);
        if (lane < 16) {
            redm[wr*256 + wc*64 + nf*16 + l15] = pmv;
            reds[wr*256 + wc*64 + nf*16 + l15] = psv;
        }
    }
    __syncthreads();
    if (t < 256) {
        pmax[(size_t)by * Vp + v0 + t] = fmaxf(redm[t], redm[256+t]);
        psum[(size_t)by * Vp + v0 + t] = reds[t] + reds[256+t];
    }
}

// ---------- blend: node max over batch tiles + graph from psum ----------
__global__ void blend_kernel(const float* __restrict__ pmax, const float* __restrict__ psum,
                             const float* __restrict__ invk, const float* __restrict__ alpha_raw,
                             float* __restrict__ out_fused, float* __restrict__ out_alpha,
                             int V, int Vp)
{
    int v = blockIdx.x * 256 + threadIdx.x;
    float alpha = 1.0f / (1.0f + expf(-alpha_raw[0]));
    if (blockIdx.x == 0 && threadIdx.x == 0) out_alpha[0] = alpha;
    if (v >= V) return;
    float ik = invk[v];
    #pragma unroll
    for (int b = 0; b < BQ; ++b) {
        float nm = fmaxf(pmax[(size_t)(2*b)*Vp + v], pmax[(size_t)(2*b+1)*Vp + v]) * ik;
        float gs = (psum[(size_t)(2*b)*Vp + v] + psum[(size_t)(2*b+1)*Vp + v]) * ik * (1.0f/(float)NQ);
        out_fused[(size_t)b*V + v] = alpha*nm + (1.0f-alpha)*gs;
    }
}

// ---------- per-batch top-64 via 4-pass radix select + bitonic order ----------
__device__ __forceinline__ unsigned int mono_map(float f)
{
    unsigned int u = __float_as_uint(f);
    return u ^ ((u & 0x80000000u) ? 0xFFFFFFFFu : 0x80000000u);
}

__global__ __launch_bounds__(1024)
void topk_radix_kernel(const float* __restrict__ fused,
                       int* __restrict__ idxout, float* __restrict__ out_idx, int V)
{
    const int b = blockIdx.x, t = threadIdx.x;
    const float* row = fused + (size_t)b * V;

    __shared__ unsigned int hist[256];
    __shared__ unsigned int sh_pref;
    __shared__ int sh_kneed;
    __shared__ unsigned int sh_nA, sh_nE;
    __shared__ unsigned long long key[64];
    __shared__ int eqIdx[256];

    unsigned int pref = 0;
    int kneed = KSEL;
    #pragma unroll
    for (int p = 24; p >= 0; p -= 8) {
        if (t < 256) hist[t] = 0;
        __syncthreads();
        unsigned int mask = (p == 24) ? 0u : (0xFFFFFFFFu << (p + 8));
        for (int i = t; i < V; i += 1024) {
            unsigned int u = mono_map(row[i]);
            if ((u & mask) == pref)
                atomicAdd(&hist[(u >> p) & 255u], 1u);
        }
        __syncthreads();
        if (t == 0) {
            int cum = 0, sel = 0;
            for (int bb = 255; bb >= 0; --bb) {
                int c = (int)hist[bb];
                if (cum + c >= kneed) { sel = bb; break; }
                cum += c;
            }
            sh_pref  = pref | ((unsigned int)sel << p);
            sh_kneed = kneed - cum;
        }
        __syncthreads();
        pref  = sh_pref;
        kneed = sh_kneed;
        __syncthreads();
    }

    const unsigned int T = pref;            // exact 64th-largest mapped value
    if (t == 0) { sh_nA = 0; sh_nE = 0; }
    __syncthreads();
    for (int i = t; i < V; i += 1024) {
        unsigned int u = mono_map(row[i]);
        if (u > T) {
            unsigned int pos = atomicAdd(&sh_nA, 1u);
            if (pos < 64) key[pos] = ((unsigned long long)(~u) << 32) | (unsigned int)i;
        } else if (u == T) {
            unsigned int pos = atomicAdd(&sh_nE, 1u);
            if (pos < 256) eqIdx[pos] = i;
        }
    }
    __syncthreads();
    const int nA = (int)sh_nA;              // < 64 by radix invariant
    const int nE = (int)sh_nE;
    if (t < 256 && t >= min(nE, 256)) eqIdx[t] = 0x7fffffff;
    __syncthreads();
    if (nE > 1) {                            // sort tie indices ascending
        for (int k = 2; k <= 256; k <<= 1)
            for (int j = k >> 1; j > 0; j >>= 1) {
                if (t < 256) {
                    int ixj = t ^ j;
                    if (ixj > t) {
                        int a = eqIdx[t], c = eqIdx[ixj];
                        bool up = ((t & k) == 0);
                        if ((a > c) == up) { eqIdx[t] = c; eqIdx[ixj] = a; }
                    }
                }
                __syncthreads();
            }
    }
    if (t < kneed)
        key[nA + t] = ((unsigned long long)(~T) << 32) | (unsigned int)eqIdx[t];
    __syncthreads();
    // sort 64 keys ascending == (value desc, idx asc)
    for (int k = 2; k <= 64; k <<= 1)
        for (int j = k >> 1; j > 0; j >>= 1) {
            if (t < 64) {
                int ixj = t ^ j;
                if (ixj > t) {
                    unsigned long long a = key[t], c = key[ixj];
                    bool up = ((t & k) == 0);
                    if ((a > c) == up) { key[t] = c; key[ixj] = a; }
                }
            }
            __syncthreads();
        }
    if (t < KSEL) {
        int idx = (int)(unsigned int)(key[t] & 0xFFFFFFFFull);
        idxout[b*KSEL + t]  = idx;
        out_idx[b*KSEL + t] = (float)idx;
    }
}

// ---------- gather selected key rows ----------
__global__ void gather_kernel(const int* __restrict__ idx, const float* __restrict__ Kmat,
                              float* __restrict__ out_sel)
{
    int j = blockIdx.x & 63, b = blockIdx.x >> 6, t = threadIdx.x;
    int sel = idx[b*KSEL + j];
    float4 v = *reinterpret_cast<const float4*>(Kmat + (size_t)sel * D + t*4);
    *reinterpret_cast<float4*>(out_sel + ((size_t)(b*KSEL + j)) * D + t*4) = v;
}

// =====================================================================
// FALLBACK PATH (round-2, known-good) — used when ws_size is too small
// =====================================================================
#define BMT 128
#define BVT 128
#define NSTEP (D/32)

__global__ void row_invnorm_kernel(const float* __restrict__ x, float* __restrict__ inv, int rows)
{
    int wid  = (blockIdx.x * blockDim.x + threadIdx.x) >> 6;
    int lane = threadIdx.x & 63;
    if (wid >= rows) return;
    const float* r = x + (size_t)wid * D;
    float ss = 0.f;
    #pragma unroll
    for (int s = 0; s < 3; ++s) {
        float4 v = *reinterpret_cast<const float4*>(r + s*256 + lane*4);
        ss += v.x*v.x + v.y*v.y + v.z*v.z + v.w*v.w;
    }
    #pragma unroll
    for (int off = 32; off > 0; off >>= 1)
        ss += __shfl_xor(ss, off, 64);
    if (lane == 0) inv[wid] = 1.0f / fmaxf(sqrtf(ss), 1e-12f);
}

__global__ void compute_gq_kernel(const float* __restrict__ q, const float* __restrict__ invq,
                                  float* __restrict__ gq)
{
    int t = blockIdx.x * blockDim.x + threadIdx.x;
    if (t >= BQ*D) return;
    int b = t / D, d = t - b*D;
    float acc = 0.f;
    const float* qb = q + (size_t)b * NQ * D + d;
    const float* iq = invq + b*NQ;
    for (int n = 0; n < NQ; ++n)
        acc += iq[n] * qb[(size_t)n*D];
    gq[t] = acc * (1.0f/(float)NQ);
}

__device__ __forceinline__ void split8(float4 a, float4 b, uint4& hi, uint4& lo)
{
    unsigned int h0,h1,h2,h3,h4,h5,h6,h7, l0,l1,l2,l3,l4,l5,l6,l7;
    split1(a.x,h0,l0); split1(a.y,h1,l1); split1(a.z,h2,l2); split1(a.w,h3,l3);
    split1(b.x,h4,l4); split1(b.y,h5,l5); split1(b.z,h6,l6); split1(b.w,h7,l7);
    hi.x = h0 | (h1<<16); hi.y = h2 | (h3<<16); hi.z = h4 | (h5<<16); hi.w = h6 | (h7<<16);
    lo.x = l0 | (l1<<16); lo.y = l2 | (l3<<16); lo.z = l4 | (l5<<16); lo.w = l6 | (l7<<16);
}

__global__ __launch_bounds__(256)
void mfma_gemm_maxpool(const float* __restrict__ Q, const float* __restrict__ Kmat,
                       const float* __restrict__ invq, const float* __restrict__ invk,
                       float* __restrict__ partial, int V, int Vp)
{
    __shared__ __align__(16) unsigned short lds[16384];
    const int t    = threadIdx.x;
    const int lane = t & 63;
    const int w    = t >> 6;
    const int wr   = w >> 1;
    const int wc   = w & 1;
    const int v0   = blockIdx.x * BVT;
    const int m0   = blockIdx.y * BMT;

    const int srow = t >> 1;
    const int scol = (t & 1) * 16;
    const int c0   = (t & 1) * 2;
    const unsigned int ps0 = (c0     + (srow >> 1)) & 3;
    const unsigned int ps1 = (c0 + 1 + (srow >> 1)) & 3;
    const unsigned int wO0 = srow*32 + ps0*8;
    const unsigned int wO1 = srow*32 + ps1*8;

    const float* Ap = Q + (size_t)(m0 + srow) * D + scol;
    int vrow = v0 + srow; if (vrow > V-1) vrow = V-1;
    const float* Bp = Kmat + (size_t)vrow * D + scol;

    const int lr = lane & 15, kg = lane >> 4;
    const int arowb = wr*64 + lr;
    const int browb = wc*64 + lr;
    const unsigned int slotA = (kg + (arowb >> 1)) & 3;
    const unsigned int slotB = (kg + (browb >> 1)) & 3;
    const unsigned int offA = arowb*32 + slotA*8;
    const unsigned int offB = browb*32 + slotB*8;

    f32x4 acc[4][4];
    #pragma unroll
    for (int i = 0; i < 4; ++i)
        #pragma unroll
        for (int j = 0; j < 4; ++j)
            acc[i][j] = f32x4{0.f,0.f,0.f,0.f};

    float4 ra0,ra1,ra2,ra3, rb0,rb1,rb2,rb3;
    #define LOADSTEP(s_) do { \
        const float* ap_ = Ap + (s_)*32; const float* bp_ = Bp + (s_)*32; \
        ra0 = *(const float4*)(ap_);    ra1 = *(const float4*)(ap_+4); \
        ra2 = *(const float4*)(ap_+8);  ra3 = *(const float4*)(ap_+12); \
        rb0 = *(const float4*)(bp_);    rb1 = *(const float4*)(bp_+4); \
        rb2 = *(const float4*)(bp_+8);  rb3 = *(const float4*)(bp_+12); \
    } while(0)

    LOADSTEP(0);
    for (int s = 0; s < NSTEP; ++s) {
        uint4 ah0,al0, ah1,al1, bh0,bl0, bh1,bl1;
        split8(ra0,ra1, ah0,al0); split8(ra2,ra3, ah1,al1);
        split8(rb0,rb1, bh0,bl0); split8(rb2,rb3, bh1,bl1);
        __syncthreads();
        *(uint4*)&lds[        wO0] = ah0;  *(uint4*)&lds[ 4096 + wO0] = al0;
        *(uint4*)&lds[        wO1] = ah1;  *(uint4*)&lds[ 4096 + wO1] = al1;
        *(uint4*)&lds[ 8192 + wO0] = bh0;  *(uint4*)&lds[12288 + wO0] = bl0;
        *(uint4*)&lds[ 8192 + wO1] = bh1;  *(uint4*)&lds[12288 + wO1] = bl1;
        if (s + 1 < NSTEP) LOADSTEP(s + 1);
        __syncthreads();

        bf16x8 Ah[4], Al[4], Bh[4], Bl[4];
        #pragma unroll
        for (int fm = 0; fm < 4; ++fm) {
            unsigned int o = offA + fm*512;
            Ah[fm] = *(const bf16x8*)&lds[o];
            Al[fm] = *(const bf16x8*)&lds[4096 + o];
        }
        #pragma unroll
        for (int fv = 0; fv < 4; ++fv) {
            unsigned int o = offB + fv*512;
            Bh[fv] = *(const bf16x8*)&lds[8192 + o];
            Bl[fv] = *(const bf16x8*)&lds[12288 + o];
        }
        #pragma unroll
        for (int fm = 0; fm < 4; ++fm)
            #pragma unroll
            for (int fv = 0; fv < 4; ++fv) {
                acc[fm][fv] = __builtin_amdgcn_mfma_f32_16x16x32_bf16(Ah[fm], Bh[fv], acc[fm][fv], 0,0,0);
                acc[fm][fv] = __builtin_amdgcn_mfma_f32_16x16x32_bf16(Ah[fm], Bl[fv], acc[fm][fv], 0,0,0);
                acc[fm][fv] = __builtin_amdgcn_mfma_f32_16x16x32_bf16(Al[fm], Bh[fv], acc[fm][fv], 0,0,0);
            }
    }
    #undef LOADSTEP

    __syncthreads();
    float* red = (float*)lds;
    float iq[4][4];
    #pragma unroll
    for (int fm = 0; fm < 4; ++fm)
        #pragma unroll
        for (int r = 0; r < 4; ++r)
            iq[fm][r] = invq[m0 + wr*64 + fm*16 + kg*4 + r];
    #pragma unroll
    for (int fv = 0; fv < 4; ++fv) {
        float tm = -INFINITY;
        #pragma unroll
        for (int fm = 0; fm < 4; ++fm)
            #pragma unroll
            for (int r = 0; r < 4; ++r)
                tm = fmaxf(tm, acc[fm][fv][r] * iq[fm][r]);
        tm = fmaxf(tm, __shfl_xor(tm, 16, 64));
        tm = fmaxf(tm, __shfl_xor(tm, 32, 64));
        if (lane < 16) red[wr*128 + wc*64 + fv*16 + lane] = tm;
    }
    __syncthreads();
    if (t < 128) {
        int v = v0 + t;
        if (v < V)
            partial[(size_t)blockIdx.y * Vp + v] = fmaxf(red[t], red[128 + t]) * invk[v];
    }
}

__global__ void fused_sim_kernel(const float* __restrict__ Kmat, const float* __restrict__ invk,
                                 const float* __restrict__ gq, const float* __restrict__ partial,
                                 const float* __restrict__ alpha_raw,
                                 float* __restrict__ out_fused, float* __restrict__ out_alpha,
                                 int V, int Vp)
{
    int wib  = threadIdx.x >> 6;
    int lane = threadIdx.x & 63;
    float alpha = 1.0f / (1.0f + expf(-alpha_raw[0]));
    if (blockIdx.x == 0 && threadIdx.x == 0) out_alpha[0] = alpha;
    int v = blockIdx.x * 4 + wib;
    if (v >= V) return;
    const float* kr = Kmat + (size_t)v * D;
    float accb[BQ] = {0.f,0.f,0.f,0.f};
    #pragma unroll
    for (int s = 0; s < 3; ++s) {
        float4 kv = *reinterpret_cast<const float4*>(kr + s*256 + lane*4);
        #pragma unroll
        for (int b = 0; b < BQ; ++b) {
            float4 gv = *reinterpret_cast<const float4*>(gq + b*D + s*256 + lane*4);
            accb[b] += gv.x*kv.x + gv.y*kv.y + gv.z*kv.z + gv.w*kv.w;
        }
    }
    #pragma unroll
    for (int b = 0; b < BQ; ++b)
        #pragma unroll
        for (int off = 32; off > 0; off >>= 1)
            accb[b] += __shfl_xor(accb[b], off, 64);
    if (lane < BQ) {
        int b = lane;
        float node = partial[(size_t)(b*4+0)*Vp + v];
        #pragma unroll
        for (int i = 1; i < 4; ++i)
            node = fmaxf(node, partial[(size_t)(b*4+i)*Vp + v]);
        float graph = accb[b] * invk[v];
        out_fused[(size_t)b*V + v] = alpha*node + (1.0f-alpha)*graph;
    }
}

__global__ __launch_bounds__(1024)
void topk_gather_kernel(const float* __restrict__ fused, const float* __restrict__ Kmat,
                        float* __restrict__ scratch, float* __restrict__ out_sel,
                        float* __restrict__ out_idx, int V, int Vp)
{
    const int b = blockIdx.x, t = threadIdx.x;
    const int lane = t & 63, wid = t >> 6;
    const float* row = fused + (size_t)b * V;
    float* s = scratch + (size_t)b * Vp;
    for (int i = t; i < V; i += 1024) s[i] = row[i];
    __syncthreads();

    const int CH = (V + 1023) / 1024;
    const int lo = t * CH;
    const int hi = min(V, lo + CH);
    float lmax = -INFINITY; int lidx = 0x7fffffff;
    for (int i = lo; i < hi; ++i) { float x = s[i]; if (x > lmax) { lmax = x; lidx = i; } }

    __shared__ float swv[16];
    __shared__ int   swi[16];
    __shared__ int   sbest;

    for (int j = 0; j < KSEL; ++j) {
        float v = lmax; int id = lidx;
        #pragma unroll
        for (int off = 32; off > 0; off >>= 1) {
            float ov = __shfl_xor(v, off, 64);
            int   oi = __shfl_xor(id, off, 64);
            if (ov > v || (ov == v && oi < id)) { v = ov; id = oi; }
        }
        if (lane == 0) { swv[wid] = v; swi[wid] = id; }
        __syncthreads();
        if (t == 0) {
            float bv = swv[0]; int bi = swi[0];
            for (int x = 1; x < 16; ++x)
                if (swv[x] > bv || (swv[x] == bv && swi[x] < bi)) { bv = swv[x]; bi = swi[x]; }
            sbest = bi;
            out_idx[b*KSEL + j] = (float)bi;
        }
        __syncthreads();
        const int sel = sbest;
        if (sel >= lo && sel < hi) {
            s[sel] = -INFINITY;
            lmax = -INFINITY; lidx = 0x7fffffff;
            for (int i = lo; i < hi; ++i) { float x = s[i]; if (x > lmax) { lmax = x; lidx = i; } }
        }
        if (t < 192) {
            float4 kv = *reinterpret_cast<const float4*>(&Kmat[(size_t)sel * D + t*4]);
            *reinterpret_cast<float4*>(&out_sel[((size_t)b*KSEL + j)*D + t*4]) = kv;
        }
        __syncthreads();
    }
}

// =====================================================================
extern "C" void kernel_launch(void* const* d_in, const int* in_sizes, int n_in,
                              void* d_out, int out_size, void* d_ws, size_t ws_size,
                              hipStream_t stream)
{
    const float* q         = (const float*)d_in[0];
    const float* kemb      = (const float*)d_in[1];
    const float* alpha_raw = (const float*)d_in[2];
    int V = in_sizes[1] / D;

    float* out_sel   = (float*)d_out;
    float* out_idx   = out_sel + BQ*KSEL*D;
    float* out_fused = out_idx + BQ*KSEL;
    float* out_alpha = out_fused + (size_t)BQ*V;

    // ---------- fast-path workspace layout ----------
    size_t Vp = (size_t)((V + 255) & ~255);
    float* ws      = (float*)d_ws;
    float* invk    = ws;                               // Vp
    float* invq    = invk + Vp;                        // M_TOTAL
    float* pmax    = invq + M_TOTAL;                   // 8*Vp
    float* psum    = pmax + 8*Vp;                      // 8*Vp
    float* scratch = psum + 8*Vp;                      // 4*Vp (unused in fast path)
    int*   idxbuf  = (int*)(scratch + 4*Vp);           // 256
    unsigned short* Qsp = (unsigned short*)(idxbuf + 256);      // M_TOTAL*1536
    unsigned short* Ksp = Qsp + (size_t)M_TOTAL * (2*D);        // Vp*1536
    size_t need = (size_t)((char*)(Ksp + Vp*(2*D)) - (char*)d_ws);

    if (ws_size >= need) {
        // ---------- FAST PATH ----------
        split_invnorm_kernel<<<M_TOTAL/8, 768, 0, stream>>>(q, Qsp, invq, M_TOTAL, M_TOTAL);
        split_invnorm_kernel<<<(int)(Vp/8), 768, 0, stream>>>(kemb, Ksp, invk, V, (int)Vp);

        hipFuncSetAttribute(reinterpret_cast<const void*>(fast_gemm),
                            hipFuncAttributeMaxDynamicSharedMemorySize, 2*SLOT_SZ);

        int gx = (int)(Vp / GBN);                      // Vp mult of 256
        fast_gemm<<<gx*8, 512, 2*SLOT_SZ, stream>>>(Qsp, Ksp, invq, pmax, psum, (int)Vp, gx);

        blend_kernel<<<(V + 255)/256, 256, 0, stream>>>(pmax, psum, invk, alpha_raw,
                                                        out_fused, out_alpha, V, (int)Vp);
        topk_radix_kernel<<<BQ, 1024, 0, stream>>>(out_fused, idxbuf, out_idx, V);
        gather_kernel<<<BQ*KSEL, 192, 0, stream>>>(idxbuf, kemb, out_sel);
    } else {
        // ---------- FALLBACK (round-2) ----------
        int Vp2 = (V + 127) & ~127;
        float* f_invk    = ws;
        float* f_invq    = f_invk + Vp2;
        float* f_gq      = f_invq + M_TOTAL;
        float* f_partial = f_gq + BQ*D;
        float* f_scratch = f_partial + (size_t)16*Vp2;

        row_invnorm_kernel<<<(V + 3)/4, 256, 0, stream>>>(kemb, f_invk, V);
        row_invnorm_kernel<<<(M_TOTAL + 3)/4, 256, 0, stream>>>(q, f_invq, M_TOTAL);
        compute_gq_kernel<<<(BQ*D + 255)/256, 256, 0, stream>>>(q, f_invq, f_gq);

        dim3 g(Vp2 / BVT, M_TOTAL / BMT);
        mfma_gemm_maxpool<<<g, 256, 0, stream>>>(q, kemb, f_invq, f_invk, f_partial, V, Vp2);

        fused_sim_kernel<<<(V + 3)/4, 256, 0, stream>>>(kemb, f_invk, f_gq, f_partial, alpha_raw,
                                                        out_fused, out_alpha, V, Vp2);
        topk_gather_kernel<<<BQ, 1024, 0, stream>>>(out_fused, kemb, f_scratch, out_sel, out_idx, V, Vp2);
    }
}